// Round 1
// baseline (754.180 us; speedup 1.0000x reference)
//
#include <hip/hip_runtime.h>

// Forward kinematics for a serial revolute chain.
// q: [B, L] fp32, axes: [L,3], t_fix: [L,3]  ->  out: [B, L, 4, 4] fp32.
// qd is an unused input in the reference (never loaded here).
//
// One thread per batch element. Rodrigues via R = c*I + s*K + (1-c)*aa^T
// (valid for unit a since K^2 = aa^T - I). Chain composed serially in
// registers; 4x float4 nontemporal stores per link (each 64B line fully
// written by a single thread -> no RMW overfetch).

typedef float v4 __attribute__((ext_vector_type(4)));

constexpr int L = 24;

__global__ __launch_bounds__(256) void fk_kernel(
    const float* __restrict__ q,
    const float* __restrict__ axes,
    const float* __restrict__ tfix,
    float* __restrict__ out,
    int nb)
{
    __shared__ float s_a[L * 3];
    __shared__ float s_t[L * 3];
    if (threadIdx.x < L) {
        const int l = threadIdx.x;
        float ax = axes[l * 3 + 0], ay = axes[l * 3 + 1], az = axes[l * 3 + 2];
        float inv = rsqrtf(ax * ax + ay * ay + az * az);
        s_a[l * 3 + 0] = ax * inv;
        s_a[l * 3 + 1] = ay * inv;
        s_a[l * 3 + 2] = az * inv;
        s_t[l * 3 + 0] = tfix[l * 3 + 0];
        s_t[l * 3 + 1] = tfix[l * 3 + 1];
        s_t[l * 3 + 2] = tfix[l * 3 + 2];
    }
    __syncthreads();

    const int b = blockIdx.x * 256 + threadIdx.x;
    if (b >= nb) return;

    // Load this element's 24 joint angles as 6 aligned float4s.
    float qv[L];
    {
        const v4* q4 = (const v4*)(q + (size_t)b * L);
        #pragma unroll
        for (int i = 0; i < L / 4; ++i) {
            v4 v = q4[i];
            qv[4 * i + 0] = v.x;
            qv[4 * i + 1] = v.y;
            qv[4 * i + 2] = v.z;
            qv[4 * i + 3] = v.w;
        }
    }

    float R00 = 1.f, R01 = 0.f, R02 = 0.f;
    float R10 = 0.f, R11 = 1.f, R12 = 0.f;
    float R20 = 0.f, R21 = 0.f, R22 = 1.f;
    float t0 = 0.f, t1 = 0.f, t2 = 0.f;

    v4* outp = (v4*)(out + (size_t)b * (L * 16));

    #pragma unroll
    for (int l = 0; l < L; ++l) {
        const float ax = s_a[l * 3 + 0], ay = s_a[l * 3 + 1], az = s_a[l * 3 + 2];
        const float fx = s_t[l * 3 + 0], fy = s_t[l * 3 + 1], fz = s_t[l * 3 + 2];

        float s, c;
        __sincosf(qv[l], &s, &c);
        const float omc = 1.0f - c;

        const float xy = omc * ax * ay;
        const float xz = omc * ax * az;
        const float yz = omc * ay * az;
        const float J00 = c + omc * ax * ax;
        const float J11 = c + omc * ay * ay;
        const float J22 = c + omc * az * az;
        const float J01 = xy - s * az, J10 = xy + s * az;
        const float J02 = xz + s * ay, J20 = xz - s * ay;
        const float J12 = yz - s * ax, J21 = yz + s * ax;

        // translation uses the PARENT rotation (pre-update), per reference
        t0 += R00 * fx + R01 * fy + R02 * fz;
        t1 += R10 * fx + R11 * fy + R12 * fz;
        t2 += R20 * fx + R21 * fy + R22 * fz;

        // R_child = R_parent @ R_joint
        const float n00 = R00 * J00 + R01 * J10 + R02 * J20;
        const float n01 = R00 * J01 + R01 * J11 + R02 * J21;
        const float n02 = R00 * J02 + R01 * J12 + R02 * J22;
        const float n10 = R10 * J00 + R11 * J10 + R12 * J20;
        const float n11 = R10 * J01 + R11 * J11 + R12 * J21;
        const float n12 = R10 * J02 + R11 * J12 + R12 * J22;
        const float n20 = R20 * J00 + R21 * J10 + R22 * J20;
        const float n21 = R20 * J01 + R21 * J11 + R22 * J21;
        const float n22 = R20 * J02 + R21 * J12 + R22 * J22;
        R00 = n00; R01 = n01; R02 = n02;
        R10 = n10; R11 = n11; R12 = n12;
        R20 = n20; R21 = n21; R22 = n22;

        v4 r0 = {R00, R01, R02, t0};
        v4 r1 = {R10, R11, R12, t1};
        v4 r2 = {R20, R21, R22, t2};
        v4 r3 = {0.f, 0.f, 0.f, 1.f};
        __builtin_nontemporal_store(r0, outp + 4 * l + 0);
        __builtin_nontemporal_store(r1, outp + 4 * l + 1);
        __builtin_nontemporal_store(r2, outp + 4 * l + 2);
        __builtin_nontemporal_store(r3, outp + 4 * l + 3);
    }
}

extern "C" void kernel_launch(void* const* d_in, const int* in_sizes, int n_in,
                              void* d_out, int out_size, void* d_ws, size_t ws_size,
                              hipStream_t stream) {
    const float* q    = (const float*)d_in[0];
    // d_in[1] = qd: unused by the reference output
    const float* axes = (const float*)d_in[2];
    const float* tfix = (const float*)d_in[3];
    float* out = (float*)d_out;

    const int nb = in_sizes[0] / L;   // 131072
    const int grid = (nb + 255) / 256;
    fk_kernel<<<grid, 256, 0, stream>>>(q, axes, tfix, out, nb);
}

// Round 2
// 244.168 us; speedup vs baseline: 3.0888x; 3.0888x over previous
//
#include <hip/hip_runtime.h>

// Forward kinematics for a serial revolute chain.
// q: [B, L] fp32, axes: [L,3], t_fix: [L,3]  ->  out: [B, L, 4, 4] fp32.
// qd is unused by the reference output (never read).
//
// 4 lanes per batch element, one OUTPUT ROW each. Key identity: row i of
// R_child = R_parent @ J depends only on row i of R_parent, and
// t_i += row_i(R_parent) . t_fix. So each lane carries only 4 floats of
// state (Ra,Rb,Rc,t) and emits one dwordx4 store per link. The 4 lanes of
// a group write 16B each, contiguous within one 64B line, in the SAME
// store instruction -> full-line coalesced writes (round 1 showed 2.9x
// write amplification from per-lane scattered 16B nontemporal stores).
// Lane 3 inits to (0,0,0, t=1); the uniform recurrence keeps it at
// (0,0,0,1) -- branch-free bottom row.

typedef float v4 __attribute__((ext_vector_type(4)));

constexpr int L = 24;

__global__ __launch_bounds__(256) void fk_kernel(
    const float* __restrict__ q,
    const float* __restrict__ axes,
    const float* __restrict__ tfix,
    float* __restrict__ out,
    int nb)
{
    __shared__ float s_a[L * 3];
    __shared__ float s_t[L * 3];
    if (threadIdx.x < L) {
        const int l = threadIdx.x;
        float ax = axes[l * 3 + 0], ay = axes[l * 3 + 1], az = axes[l * 3 + 2];
        float inv = rsqrtf(ax * ax + ay * ay + az * az);
        s_a[l * 3 + 0] = ax * inv;
        s_a[l * 3 + 1] = ay * inv;
        s_a[l * 3 + 2] = az * inv;
        s_t[l * 3 + 0] = tfix[l * 3 + 0];
        s_t[l * 3 + 1] = tfix[l * 3 + 1];
        s_t[l * 3 + 2] = tfix[l * 3 + 2];
    }
    __syncthreads();

    const int gtid = blockIdx.x * 256 + threadIdx.x;
    const int b = gtid >> 2;        // batch element
    const int r = gtid & 3;         // output row owned by this lane
    if (b >= nb) return;

    // Load this element's 24 joint angles (redundant across the 4-lane
    // group; L1 broadcast handles it).
    float qv[L];
    {
        const v4* q4 = (const v4*)(q + (size_t)b * L);
        #pragma unroll
        for (int i = 0; i < L / 4; ++i) {
            v4 v = q4[i];
            qv[4 * i + 0] = v.x;
            qv[4 * i + 1] = v.y;
            qv[4 * i + 2] = v.z;
            qv[4 * i + 3] = v.w;
        }
    }

    // Row r of the identity pose; row 3 -> (0,0,0,1).
    float Ra = (r == 0) ? 1.f : 0.f;
    float Rb = (r == 1) ? 1.f : 0.f;
    float Rc = (r == 2) ? 1.f : 0.f;
    float t  = (r == 3) ? 1.f : 0.f;

    v4* outp = (v4*)(out + (size_t)b * (L * 16) + r * 4);

    #pragma unroll
    for (int l = 0; l < L; ++l) {
        const float ax = s_a[l * 3 + 0], ay = s_a[l * 3 + 1], az = s_a[l * 3 + 2];
        const float fx = s_t[l * 3 + 0], fy = s_t[l * 3 + 1], fz = s_t[l * 3 + 2];

        float s, c;
        __sincosf(qv[l], &s, &c);
        const float omc = 1.0f - c;

        // Rodrigues for unit axis a: J = c*I + s*K + (1-c) a a^T
        const float xy = omc * ax * ay;
        const float xz = omc * ax * az;
        const float yz = omc * ay * az;
        const float J00 = c + omc * ax * ax;
        const float J11 = c + omc * ay * ay;
        const float J22 = c + omc * az * az;
        const float J01 = xy - s * az, J10 = xy + s * az;
        const float J02 = xz + s * ay, J20 = xz - s * ay;
        const float J12 = yz - s * ax, J21 = yz + s * ax;

        // translation uses the PARENT rotation row (pre-update)
        t += Ra * fx + Rb * fy + Rc * fz;

        // row r of R_child = row r of R_parent @ J
        const float na = Ra * J00 + Rb * J10 + Rc * J20;
        const float nb_ = Ra * J01 + Rb * J11 + Rc * J21;
        const float nc = Ra * J02 + Rb * J12 + Rc * J22;
        Ra = na; Rb = nb_; Rc = nc;

        v4 row = {Ra, Rb, Rc, t};
        __builtin_nontemporal_store(row, outp + 4 * l);
    }
}

extern "C" void kernel_launch(void* const* d_in, const int* in_sizes, int n_in,
                              void* d_out, int out_size, void* d_ws, size_t ws_size,
                              hipStream_t stream) {
    const float* q    = (const float*)d_in[0];
    // d_in[1] = qd: unused by the reference output
    const float* axes = (const float*)d_in[2];
    const float* tfix = (const float*)d_in[3];
    float* out = (float*)d_out;

    const int nb = in_sizes[0] / L;           // 131072
    const long long nthreads = (long long)nb * 4;
    const int grid = (int)((nthreads + 255) / 256);
    fk_kernel<<<grid, 256, 0, stream>>>(q, axes, tfix, out, nb);
}

// Round 4
// 221.330 us; speedup vs baseline: 3.4075x; 1.1032x over previous
//
#include <hip/hip_runtime.h>

// Forward kinematics for a serial revolute chain.
// q: [B, L] fp32, axes: [L,3], t_fix: [L,3]  ->  out: [B, L, 4, 4] fp32.
// qd is unused by the reference output (never read).
//
// 4 lanes per batch element, one OUTPUT ROW each (row i of R_parent@J
// depends only on row i of R_parent). Each wave owns 16 elements = 24KB
// of output, staged in LDS during the recurrence, then drained with 24
// wave-wide dwordx4 stores (64 lanes x 16B = 1KB of lane-consecutive
// addresses per instruction -- round 3's bug was draining only 6 of the
// required 24 stores, leaving 3/4 of the output unwritten).
//
// LDS element stride padded 384->388 words (388 % 32 == 4) so the
// ds_write_b128 pattern lands 8 lanes on each 4-bank group (the wave64
// minimum). 128-thread blocks -> ~50KB LDS -> 3 blocks/CU.

typedef float v4 __attribute__((ext_vector_type(4)));

constexpr int L = 24;
constexpr int EW = 384;        // output words per element (L*16)
constexpr int EWP = 388;       // padded LDS stride per element (words)
constexpr int WAVE_WORDS = 16 * EWP;  // 6208 words per wave

__global__ __launch_bounds__(128) void fk_kernel(
    const float* __restrict__ q,
    const float* __restrict__ axes,
    const float* __restrict__ tfix,
    float* __restrict__ out,
    int nb)
{
    __shared__ float s_a[L * 3];
    __shared__ float s_t[L * 3];
    __shared__ float s_buf[2 * WAVE_WORDS];   // 2 waves * 24832 B

    if (threadIdx.x < L) {
        const int l = threadIdx.x;
        float ax = axes[l * 3 + 0], ay = axes[l * 3 + 1], az = axes[l * 3 + 2];
        float inv = rsqrtf(ax * ax + ay * ay + az * az);
        s_a[l * 3 + 0] = ax * inv;
        s_a[l * 3 + 1] = ay * inv;
        s_a[l * 3 + 2] = az * inv;
        s_t[l * 3 + 0] = tfix[l * 3 + 0];
        s_t[l * 3 + 1] = tfix[l * 3 + 1];
        s_t[l * 3 + 2] = tfix[l * 3 + 2];
    }
    __syncthreads();

    const int tid  = threadIdx.x;
    const int wave = tid >> 6;
    const int lane = tid & 63;
    const int e    = lane >> 2;    // element within wave (0..15)
    const int r    = lane & 3;     // output row owned by this lane

    const int wave_elem0 = blockIdx.x * 32 + wave * 16;  // first element of this wave
    const int b = wave_elem0 + e;

    float* wbuf = s_buf + wave * WAVE_WORDS;

    if (b < nb) {
        // Load this element's 24 joint angles (redundant across the
        // 4-lane group; L1 broadcast absorbs it).
        float qv[L];
        {
            const v4* q4 = (const v4*)(q + (size_t)b * L);
            #pragma unroll
            for (int i = 0; i < L / 4; ++i) {
                v4 v = q4[i];
                qv[4 * i + 0] = v.x;
                qv[4 * i + 1] = v.y;
                qv[4 * i + 2] = v.z;
                qv[4 * i + 3] = v.w;
            }
        }

        // Row r of the identity pose; row 3 -> (0,0,0,1).
        float Ra = (r == 0) ? 1.f : 0.f;
        float Rb = (r == 1) ? 1.f : 0.f;
        float Rc = (r == 2) ? 1.f : 0.f;
        float t  = (r == 3) ? 1.f : 0.f;

        v4* lrow = (v4*)(wbuf + e * EWP + r * 4);   // + l*16 words per link

        #pragma unroll
        for (int l = 0; l < L; ++l) {
            const float ax = s_a[l * 3 + 0], ay = s_a[l * 3 + 1], az = s_a[l * 3 + 2];
            const float fx = s_t[l * 3 + 0], fy = s_t[l * 3 + 1], fz = s_t[l * 3 + 2];

            float s, c;
            __sincosf(qv[l], &s, &c);
            const float omc = 1.0f - c;

            // Rodrigues for unit axis a: J = c*I + s*K + (1-c) a a^T
            const float xy = omc * ax * ay;
            const float xz = omc * ax * az;
            const float yz = omc * ay * az;
            const float J00 = c + omc * ax * ax;
            const float J11 = c + omc * ay * ay;
            const float J22 = c + omc * az * az;
            const float J01 = xy - s * az, J10 = xy + s * az;
            const float J02 = xz + s * ay, J20 = xz - s * ay;
            const float J12 = yz - s * ax, J21 = yz + s * ax;

            // translation uses the PARENT rotation row (pre-update)
            t += Ra * fx + Rb * fy + Rc * fz;

            // row r of R_child = row r of R_parent @ J
            const float na  = Ra * J00 + Rb * J10 + Rc * J20;
            const float nb_ = Ra * J01 + Rb * J11 + Rc * J21;
            const float nc  = Ra * J02 + Rb * J12 + Rc * J22;
            Ra = na; Rb = nb_; Rc = nc;

            lrow[l * 4] = v4{Ra, Rb, Rc, t};
        }
    }
    __syncthreads();

    // Drain: 24 wave-wide 1KB-contiguous nontemporal stores covering all
    // 16*384 = 6144 words this wave owns.
    if (wave_elem0 < nb) {
        float* gbase = out + (size_t)wave_elem0 * EW;
        #pragma unroll
        for (int j = 0; j < 24; ++j) {
            const unsigned w = (unsigned)(j * 256 + lane * 4); // flat word in [0, 6144)
            const unsigned elem = w / EW;
            const unsigned rem  = w - elem * EW;
            v4 v = *(const v4*)(wbuf + elem * EWP + rem);
            __builtin_nontemporal_store(v, (v4*)(gbase + w));
        }
    }
}

extern "C" void kernel_launch(void* const* d_in, const int* in_sizes, int n_in,
                              void* d_out, int out_size, void* d_ws, size_t ws_size,
                              hipStream_t stream) {
    const float* q    = (const float*)d_in[0];
    // d_in[1] = qd: unused by the reference output
    const float* axes = (const float*)d_in[2];
    const float* tfix = (const float*)d_in[3];
    float* out = (float*)d_out;

    const int nb = in_sizes[0] / L;                 // 131072
    const long long nthreads = (long long)nb * 4;   // 4 lanes per element
    const int grid = (int)((nthreads + 127) / 128);
    fk_kernel<<<grid, 128, 0, stream>>>(q, axes, tfix, out, nb);
}